// Round 7
// baseline (360.051 us; speedup 1.0000x reference)
//
#include <hip/hip_runtime.h>
#include <stdint.h>

typedef short v8s __attribute__((ext_vector_type(8)));
typedef short v4s __attribute__((ext_vector_type(4)));
typedef float v4f __attribute__((ext_vector_type(4)));

#define BM 128
#define BN 128
#define BK 64          // shorts per row per k-chunk (128 B)
#define POS_INF __builtin_inff()

typedef __attribute__((address_space(3))) unsigned int lds_uint;
typedef const __attribute__((address_space(1))) unsigned int glb_uint;

__device__ __forceinline__ void load16_lds(const void* g, void* l) {
    // 16B per lane, LDS dest = wave-uniform base + lane*16
    __builtin_amdgcn_global_load_lds((glb_uint*)g, (lds_uint*)l, 16, 0, 0);
}

__device__ __forceinline__ short f2bf(float f) {
    uint32_t u = __builtin_bit_cast(uint32_t, f);
    u += 0x7fffu + ((u >> 16) & 1u);
    return (short)(u >> 16);
}

// prep: normalize centers rows (fp32 math) -> bf16, pad rows [C, CP) with
// zeros; zero the rowblock counters and d_out. 4 rows/block (1 per wave).
__global__ void prep(const float* __restrict__ centers,
                     unsigned short* __restrict__ cbf,
                     int C, int D, int CP,
                     int* __restrict__ cnt, int NB,
                     float* __restrict__ out) {
    const int b = blockIdx.x;
    const int t = threadIdx.x;
    if (b == 0 && t == 0) out[0] = 0.0f;
    {
        const int g = b * 256 + t;
        if (g < NB) cnt[g] = 0;
    }
    const int wave = t >> 6, lane = t & 63;
    const int row = b * 4 + wave;
    if (row >= CP) return;
    if (row >= C) {
        v4s z = {0, 0, 0, 0};
        for (int d = lane * 4; d < D; d += 256)
            *(v4s*)&cbf[(size_t)row * D + d] = z;
        return;
    }
    const float* src = centers + (size_t)row * D;
    float ss = 0.0f;
    for (int d = lane * 4; d < D; d += 256) {
        v4f f = *(const v4f*)&src[d];
        ss += f.x * f.x + f.y * f.y + f.z * f.z + f.w * f.w;
    }
    #pragma unroll
    for (int off = 32; off; off >>= 1) ss += __shfl_xor(ss, off, 64);
    const float rn = rsqrtf(ss);
    for (int d = lane * 4; d < D; d += 256) {
        v4f f = *(const v4f*)&src[d];
        v4s s;
        s.x = f2bf(f.x * rn); s.y = f2bf(f.y * rn);
        s.z = f2bf(f.z * rn); s.w = f2bf(f.w * rn);
        *(v4s*)&cbf[(size_t)row * D + d] = s;
    }
}

// Fused GEMM + row-min epilogue + last-block-per-rowblock loss finisher.
// 1D grid, XCD-swizzled: xcd = bid&7; each XCD runs all NT n-tiles of its
// row-blocks consecutively, so the rowblock's fp32 x-slab (256 KB) is read
// from HBM once and then served from that XCD's L2 for the other 7 tiles.
// A is staged DIRECTLY from fp32 with in-flight bf16 conversion (manual
// ds_write_b128, XOR-swizzled layout); B via global_load_lds DMA.
// Wave tile 64x64 = 4x4 of mfma_f32_16x16x32_bf16 (proven 0-conflict LDS
// geometry; the 32x32 variant's lane->chunk map conflicts -- round 4).
// LDS invariant: row r, slot chunk s holds source chunk s^(r&7).
//
// Cross-block protocol: NO acquire/release fences (agent-scope ACQ_REL RMW
// emits buffer_inv/buffer_wbl2 = per-XCD L2 flush; round 5 measured +59%
// k-loop time). pos/partial use RELAXED agent-scope atomics (write-through
// past the non-coherent L2); __syncthreads drains vmcnt(0) before the
// RELAXED counter RMW; RMW total order + control dependency orders the
// finisher's relaxed loads after all 8 writers.
__global__ void gemm_fused(const float* __restrict__ x,
                           const unsigned short* __restrict__ cbf,
                           const int* __restrict__ labels,
                           float* __restrict__ pos, float* __restrict__ partial,
                           int* __restrict__ cnt,
                           int Bt, int C, int D, int NT, float margin,
                           float* __restrict__ out) {
    __shared__ short LDSbuf[2 * BM * BK];   // 32 KB total
    short* As = LDSbuf;
    short* Bs = LDSbuf + BM * BK;

    const int t   = threadIdx.x;
    const int bid = blockIdx.x;
    const int xcd = bid & 7;
    const int per = bid >> 3;
    const int rowblk = (per >> 3) * 8 + xcd;
    const int nt     = per & 7;
    const int row0 = rowblk * BM;
    const int n0   = nt * BN;

    const int lane = t & 63;
    const int wave = t >> 6;
    const int wm = wave >> 1, wn = wave & 1;
    const int l15 = lane & 15, q = lane >> 4;

    // B staging lane decomposition: 8 rows x 8 chunks per DMA instruction
    const int rsub = lane >> 3;              // row within 8-row group
    const int csrc = (lane & 7) ^ rsub;      // swizzled source chunk

    // A staging decomposition (manual): 32 rows x 8 chunks per block pass
    const int ar = t >> 3;                   // 0..31
    const int acs = t & 7;                   // source chunk 0..7

    v4f acc[4][4];
    #pragma unroll
    for (int i = 0; i < 4; ++i)
        #pragma unroll
        for (int j = 0; j < 4; ++j)
            acc[i][j] = (v4f){0.f, 0.f, 0.f, 0.f};

    const int KT = D / BK;
    for (int kk = 0; kk < KT; ++kk) {
        const int k0 = kk * BK;
        // stage B tile via global_load_lds: 4 instrs/wave (32 rows/wave)
        #pragma unroll
        for (int p = 0; p < 4; ++p) {
            const int rbase = wave * 32 + p * 8;
            const unsigned short* g =
                &cbf[(size_t)(n0 + rbase + rsub) * D + k0 + csrc * 8];
            load16_lds(g, &Bs[rbase * BK]);
        }
        // stage A tile from fp32: load 8 floats, convert, ds_write_b128 into
        // the swizzled slot (source chunk acs -> slot acs^(r&7)).
        #pragma unroll
        for (int p = 0; p < 4; ++p) {
            const int r = ar + p * 32;
            const float* src = &x[(size_t)(row0 + r) * D + k0 + acs * 8];
            v4f f0 = *(const v4f*)&src[0];
            v4f f1 = *(const v4f*)&src[4];
            v8s s;
            s[0] = f2bf(f0.x); s[1] = f2bf(f0.y);
            s[2] = f2bf(f0.z); s[3] = f2bf(f0.w);
            s[4] = f2bf(f1.x); s[5] = f2bf(f1.y);
            s[6] = f2bf(f1.z); s[7] = f2bf(f1.w);
            *(v8s*)&As[r * BK + ((acs ^ (r & 7)) * 8)] = s;
        }
        __syncthreads();
        #pragma unroll
        for (int ki = 0; ki < BK; ki += 32) {
            const int cbase = ki >> 3;  // chunk base (0 or 4)
            v8s a[4], b[4];
            #pragma unroll
            for (int i = 0; i < 4; ++i) {
                const int m = wm * 64 + i * 16 + l15;
                a[i] = *(const v8s*)&As[m * BK + (((cbase + q) ^ (l15 & 7)) * 8)];
            }
            #pragma unroll
            for (int j = 0; j < 4; ++j) {
                const int n = wn * 64 + j * 16 + l15;
                b[j] = *(const v8s*)&Bs[n * BK + (((cbase + q) ^ (l15 & 7)) * 8)];
            }
            #pragma unroll
            for (int i = 0; i < 4; ++i)
                #pragma unroll
                for (int j = 0; j < 4; ++j)
                    acc[i][j] = __builtin_amdgcn_mfma_f32_16x16x32_bf16(
                        a[i], b[j], acc[i][j], 0, 0, 0);
        }
        __syncthreads();
    }

    // ---- Epilogue (As/Bs dead; alias scratch) ----
    int*   Ls    = (int*)As;                 // [BM] (512 B)
    float* sMinW = (float*)Bs;               // [2*BM] (1 KB)
    int*   sLast = (int*)(Bs + 2 * BM * 2);  // 1 int at Bs+1024B
    float* wsum  = (float*)(sLast + 1);      // 4 floats
    if (t < BM) Ls[t] = labels[row0 + t];
    __syncthreads();

    // dist = 1 - acc; stash pos at label col; row-min over valid cols.
    // C/D layout (16x16x32): col = lane&15, row = q*4 + reg
    #pragma unroll
    for (int i = 0; i < 4; ++i) {
        #pragma unroll
        for (int rg = 0; rg < 4; ++rg) {
            const int row_l = wm * 64 + i * 16 + q * 4 + rg;
            const int lab = Ls[row_l];
            float m = POS_INF;
            #pragma unroll
            for (int j = 0; j < 4; ++j) {
                const int col = n0 + wn * 64 + j * 16 + l15;
                const float d = 1.0f - acc[i][j][rg];
                if (col == lab)
                    __hip_atomic_store(&pos[row0 + row_l], d,
                                       __ATOMIC_RELAXED, __HIP_MEMORY_SCOPE_AGENT);
                else if (col < C) m = fminf(m, d);
            }
            m = fminf(m, __shfl_xor(m, 1, 64));
            m = fminf(m, __shfl_xor(m, 2, 64));
            m = fminf(m, __shfl_xor(m, 4, 64));
            m = fminf(m, __shfl_xor(m, 8, 64));
            if (l15 == 0) sMinW[wn * BM + row_l] = m;
        }
    }
    __syncthreads();
    if (t < BM) {
        const float m = fminf(sMinW[t], sMinW[BM + t]);
        __hip_atomic_store(&partial[(size_t)nt * Bt + row0 + t], m,
                           __ATOMIC_RELAXED, __HIP_MEMORY_SCOPE_AGENT);
    }
    __syncthreads();  // drains vmcnt(0): all sc-bit stores at coherence point

    // Completion counter: RELAXED on purpose (no buffer_inv/buffer_wbl2).
    if (t == 0) {
        __builtin_amdgcn_s_waitcnt(0);  // belt-and-braces; already drained
        const int old = __hip_atomic_fetch_add(&cnt[rowblk], 1,
                                               __ATOMIC_RELAXED,
                                               __HIP_MEMORY_SCOPE_AGENT);
        *sLast = (old == NT - 1);
    }
    __syncthreads();
    if (!*sLast) return;

    float hng = 0.0f;
    if (t < BM) {
        const int r = row0 + t;
        float neg = POS_INF;
        for (int tt = 0; tt < NT; ++tt)
            neg = fminf(neg, __hip_atomic_load(&partial[(size_t)tt * Bt + r],
                                               __ATOMIC_RELAXED,
                                               __HIP_MEMORY_SCOPE_AGENT));
        const float p = __hip_atomic_load(&pos[r], __ATOMIC_RELAXED,
                                          __HIP_MEMORY_SCOPE_AGENT);
        hng = fmaxf(0.0f, p + margin - neg);
    }
    #pragma unroll
    for (int off = 32; off; off >>= 1) hng += __shfl_down(hng, off, 64);
    if (lane == 0) wsum[wave] = hng;
    __syncthreads();
    if (t == 0)
        atomicAdd(out, (wsum[0] + wsum[1] + wsum[2] + wsum[3]) * (1.0f / (float)Bt));
}

extern "C" void kernel_launch(void* const* d_in, const int* in_sizes, int n_in,
                              void* d_out, int out_size, void* d_ws, size_t ws_size,
                              hipStream_t stream) {
    const float* x       = (const float*)d_in[0];
    const int*   labels  = (const int*)d_in[1];
    const float* centers = (const float*)d_in[2];
    float* out = (float*)d_out;

    const int Bt = in_sizes[1];           // 65536
    const int D  = in_sizes[0] / Bt;      // 512
    const int C  = in_sizes[2] / D;       // 1000
    const int NT = (C + BN - 1) / BN;     // 8
    const int CP = NT * BN;               // 1024
    const int NB = Bt / BM;               // 512

    char* ws = (char*)d_ws;
    unsigned short* cbf = (unsigned short*)ws;          // CP*D bf16 = 1 MB
    size_t off = (size_t)CP * D * 2;
    off = (off + 255) & ~(size_t)255;
    float* pos = (float*)(ws + off);      off += (size_t)Bt * 4;       // 256 KB
    float* partial = (float*)(ws + off);  off += (size_t)NT * Bt * 4;  // 2 MB
    int* cnt = (int*)(ws + off);

    prep<<<CP / 4, 256, 0, stream>>>(centers, cbf, C, D, CP, cnt, NB, out);

    gemm_fused<<<NB * NT, 256, 0, stream>>>(x, cbf, labels, pos, partial, cnt,
                                            Bt, C, D, NT, 1.0f, out);
}

// Round 8
// 290.166 us; speedup vs baseline: 1.2408x; 1.2408x over previous
//
#include <hip/hip_runtime.h>
#include <stdint.h>

typedef short v8s __attribute__((ext_vector_type(8)));
typedef short v4s __attribute__((ext_vector_type(4)));
typedef float v4f __attribute__((ext_vector_type(4)));

#define BM 256         // rows per block (8 waves, wave grid 4x2)
#define BN 128
#define BK 64          // shorts per row per k-chunk (128 B)
#define POS_INF __builtin_inff()

typedef __attribute__((address_space(3))) unsigned int lds_uint;
typedef const __attribute__((address_space(1))) unsigned int glb_uint;

__device__ __forceinline__ void load16_lds(const void* g, void* l) {
    // 16B per lane, LDS dest = wave-uniform base + lane*16
    __builtin_amdgcn_global_load_lds((glb_uint*)g, (lds_uint*)l, 16, 0, 0);
}

__device__ __forceinline__ short f2bf(float f) {
    uint32_t u = __builtin_bit_cast(uint32_t, f);
    u += 0x7fffu + ((u >> 16) & 1u);
    return (short)(u >> 16);
}

// Fused prep: blocks [0, CB) normalize centers (1 row per wave) and pad rows
// [C, CP) with zeros, plus zero the rowblock counters and d_out; blocks
// [CB, ...) convert x fp32->bf16 at pure memory BW. (Round 7 proved in-GEMM
// conversion costs far more than this pass: manual staging loses the DMA
// path and stalls the k-loop.)
__global__ void prep(const float* __restrict__ centers,
                     unsigned short* __restrict__ cbf,
                     int C, int D, int CP, int CB,
                     const float* __restrict__ x,
                     unsigned short* __restrict__ xbf, size_t nx,
                     int* __restrict__ cnt, int NB,
                     float* __restrict__ out) {
    const int b = blockIdx.x;
    const int t = threadIdx.x;
    if (b == 0 && t == 0) out[0] = 0.0f;
    if (b < CB) {
        const int g = b * 256 + t;
        if (g < NB) cnt[g] = 0;
        const int wave = t >> 6, lane = t & 63;
        const int row = b * 4 + wave;
        if (row >= CP) return;
        if (row >= C) {
            v4s z = {0, 0, 0, 0};
            for (int d = lane * 4; d < D; d += 256)
                *(v4s*)&cbf[(size_t)row * D + d] = z;
            return;
        }
        const float* src = centers + (size_t)row * D;
        float ss = 0.0f;
        for (int d = lane * 4; d < D; d += 256) {
            v4f f = *(const v4f*)&src[d];
            ss += f.x * f.x + f.y * f.y + f.z * f.z + f.w * f.w;
        }
        #pragma unroll
        for (int off = 32; off; off >>= 1) ss += __shfl_xor(ss, off, 64);
        const float rn = rsqrtf(ss);
        for (int d = lane * 4; d < D; d += 256) {
            v4f f = *(const v4f*)&src[d];
            v4s s;
            s.x = f2bf(f.x * rn); s.y = f2bf(f.y * rn);
            s.z = f2bf(f.z * rn); s.w = f2bf(f.w * rn);
            *(v4s*)&cbf[(size_t)row * D + d] = s;
        }
    } else {
        const size_t i = ((size_t)(b - CB) * 256 + t) * 8;
        if (i >= nx) return;
        v4f f0 = *(const v4f*)&x[i];
        v4f f1 = *(const v4f*)&x[i + 4];
        v8s s;
        s[0] = f2bf(f0.x); s[1] = f2bf(f0.y); s[2] = f2bf(f0.z); s[3] = f2bf(f0.w);
        s[4] = f2bf(f1.x); s[5] = f2bf(f1.y); s[6] = f2bf(f1.z); s[7] = f2bf(f1.w);
        *(v8s*)&xbf[i] = s;
    }
}

// Fused GEMM + row-min epilogue + last-block-per-rowblock loss finisher.
// 256x128 block tile, 512 threads = 8 waves (wave grid 4x2, 64x64/wave).
// LDS: A 32 KB + B 16 KB = 48 KB -> 3 blocks/CU = 24 waves/CU (round 6's
// 128x128/32KB ran at only ~12 waves/CU, latency-starved).
// 1D grid, XCD-swizzled: xcd = bid&7; each XCD runs all NT n-tiles of its
// row-blocks consecutively so the A-slab (256 KB bf16) stays in its L2.
// Both A and B staged via global_load_lds DMA (no VGPR round trip).
// Wave k-loop = 4x4 of mfma_f32_16x16x32_bf16 (proven 0-conflict geometry;
// 32x32 variant conflicts -- round 4). LDS invariant: row r, slot chunk s
// holds source chunk s^(r&7); DMA writes base+lane*16 so SOURCE is permuted.
//
// Cross-block protocol: NO acquire/release fences (agent-scope ACQ_REL RMW
// emits buffer_inv/buffer_wbl2 = per-XCD L2 flush; round 5 measured +59%
// k-loop time). pos/partial use RELAXED agent-scope atomics (write-through
// past the non-coherent L2); __syncthreads drains vmcnt(0) before the
// RELAXED counter RMW; RMW total order + control dependency orders the
// finisher's relaxed loads after all 8 writers.
__global__ void __launch_bounds__(512)
gemm_fused(const unsigned short* __restrict__ xbf,
           const unsigned short* __restrict__ cbf,
           const int* __restrict__ labels,
           float* __restrict__ pos, float* __restrict__ partial,
           int* __restrict__ cnt,
           int Bt, int C, int D, int NT, float margin,
           float* __restrict__ out) {
    __shared__ short LDSbuf[(BM + BN) * BK];   // 48 KB total
    short* As = LDSbuf;                         // 32 KB
    short* Bs = LDSbuf + BM * BK;               // 16 KB

    const int t   = threadIdx.x;
    const int bid = blockIdx.x;
    const int xcd = bid & 7;
    const int per = bid >> 3;
    const int rowblk = (per >> 3) * 8 + xcd;
    const int nt     = per & 7;
    const int row0 = rowblk * BM;
    const int n0   = nt * BN;

    const int lane = t & 63;
    const int wave = t >> 6;          // 0..7
    const int wm = wave >> 1;         // 0..3 -> m offset wm*64
    const int wn = wave & 1;          // 0..1 -> n offset wn*64
    const int l15 = lane & 15, q = lane >> 4;

    // staging lane decomposition: 8 rows x 8 chunks per DMA instruction
    const int rsub = lane >> 3;              // row within 8-row group
    const int csrc = (lane & 7) ^ rsub;      // swizzled source chunk

    // prefetch this thread's label before the k-loop (latency hidden)
    int myLab = 0;
    if (t < BM) myLab = labels[row0 + t];

    v4f acc[4][4];
    #pragma unroll
    for (int i = 0; i < 4; ++i)
        #pragma unroll
        for (int j = 0; j < 4; ++j)
            acc[i][j] = (v4f){0.f, 0.f, 0.f, 0.f};

    const int KT = D / BK;
    for (int kk = 0; kk < KT; ++kk) {
        const int k0 = kk * BK;
        // stage A tile: 256 rows -> 32 DMA instrs -> 4 per wave
        #pragma unroll
        for (int p = 0; p < 4; ++p) {
            const int rbase = wave * 32 + p * 8;
            const unsigned short* g =
                &xbf[(size_t)(row0 + rbase + rsub) * D + k0 + csrc * 8];
            load16_lds(g, &As[rbase * BK]);
        }
        // stage B tile: 128 rows -> 16 DMA instrs -> 2 per wave
        #pragma unroll
        for (int p = 0; p < 2; ++p) {
            const int rbase = wave * 16 + p * 8;
            const unsigned short* g =
                &cbf[(size_t)(n0 + rbase + rsub) * D + k0 + csrc * 8];
            load16_lds(g, &Bs[rbase * BK]);
        }
        __syncthreads();
        #pragma unroll
        for (int ki = 0; ki < BK; ki += 32) {
            const int cbase = ki >> 3;  // chunk base (0 or 4)
            v8s a[4], b[4];
            #pragma unroll
            for (int i = 0; i < 4; ++i) {
                const int m = wm * 64 + i * 16 + l15;
                a[i] = *(const v8s*)&As[m * BK + (((cbase + q) ^ (l15 & 7)) * 8)];
            }
            #pragma unroll
            for (int j = 0; j < 4; ++j) {
                const int n = wn * 64 + j * 16 + l15;
                b[j] = *(const v8s*)&Bs[n * BK + (((cbase + q) ^ (l15 & 7)) * 8)];
            }
            #pragma unroll
            for (int i = 0; i < 4; ++i)
                #pragma unroll
                for (int j = 0; j < 4; ++j)
                    acc[i][j] = __builtin_amdgcn_mfma_f32_16x16x32_bf16(
                        a[i], b[j], acc[i][j], 0, 0, 0);
        }
        __syncthreads();
    }

    // ---- Epilogue (As/Bs dead; alias scratch) ----
    int*   Ls    = (int*)As;                 // [BM] (1 KB)
    float* sMinW = (float*)Bs;               // [2*BM] (2 KB)
    int*   sLast = (int*)(Bs + 2 * BM * 2);  // 1 int at Bs+2048B
    float* wsum  = (float*)(sLast + 1);      // 8 floats
    if (t < BM) Ls[t] = myLab;
    __syncthreads();

    // dist = 1 - acc; stash pos at label col; row-min over valid cols.
    // C/D layout (16x16x32): col = lane&15, row = q*4 + reg
    #pragma unroll
    for (int i = 0; i < 4; ++i) {
        #pragma unroll
        for (int rg = 0; rg < 4; ++rg) {
            const int row_l = wm * 64 + i * 16 + q * 4 + rg;
            const int lab = Ls[row_l];
            float m = POS_INF;
            #pragma unroll
            for (int j = 0; j < 4; ++j) {
                const int col = n0 + wn * 64 + j * 16 + l15;
                const float d = 1.0f - acc[i][j][rg];
                if (col == lab)
                    __hip_atomic_store(&pos[row0 + row_l], d,
                                       __ATOMIC_RELAXED, __HIP_MEMORY_SCOPE_AGENT);
                else if (col < C) m = fminf(m, d);
            }
            m = fminf(m, __shfl_xor(m, 1, 64));
            m = fminf(m, __shfl_xor(m, 2, 64));
            m = fminf(m, __shfl_xor(m, 4, 64));
            m = fminf(m, __shfl_xor(m, 8, 64));
            if (l15 == 0) sMinW[wn * BM + row_l] = m;
        }
    }
    __syncthreads();
    if (t < BM) {
        const float m = fminf(sMinW[t], sMinW[BM + t]);
        __hip_atomic_store(&partial[(size_t)nt * Bt + row0 + t], m,
                           __ATOMIC_RELAXED, __HIP_MEMORY_SCOPE_AGENT);
    }
    __syncthreads();  // drains vmcnt(0): all sc-bit stores at coherence point

    // Completion counter: RELAXED on purpose (no buffer_inv/buffer_wbl2).
    if (t == 0) {
        __builtin_amdgcn_s_waitcnt(0);  // belt-and-braces; already drained
        const int old = __hip_atomic_fetch_add(&cnt[rowblk], 1,
                                               __ATOMIC_RELAXED,
                                               __HIP_MEMORY_SCOPE_AGENT);
        *sLast = (old == NT - 1);
    }
    __syncthreads();
    if (!*sLast) return;

    float hng = 0.0f;
    if (t < BM) {
        const int r = row0 + t;
        float neg = POS_INF;
        for (int tt = 0; tt < NT; ++tt)
            neg = fminf(neg, __hip_atomic_load(&partial[(size_t)tt * Bt + r],
                                               __ATOMIC_RELAXED,
                                               __HIP_MEMORY_SCOPE_AGENT));
        const float p = __hip_atomic_load(&pos[r], __ATOMIC_RELAXED,
                                          __HIP_MEMORY_SCOPE_AGENT);
        hng = fmaxf(0.0f, p + margin - neg);
    }
    #pragma unroll
    for (int off = 32; off; off >>= 1) hng += __shfl_down(hng, off, 64);
    if (lane == 0) wsum[wave] = hng;
    __syncthreads();
    if (t == 0) {
        float s = 0.0f;
        #pragma unroll
        for (int w = 0; w < 8; ++w) s += wsum[w];
        atomicAdd(out, s * (1.0f / (float)Bt));
    }
}

extern "C" void kernel_launch(void* const* d_in, const int* in_sizes, int n_in,
                              void* d_out, int out_size, void* d_ws, size_t ws_size,
                              hipStream_t stream) {
    const float* x       = (const float*)d_in[0];
    const int*   labels  = (const int*)d_in[1];
    const float* centers = (const float*)d_in[2];
    float* out = (float*)d_out;

    const int Bt = in_sizes[1];           // 65536
    const int D  = in_sizes[0] / Bt;      // 512
    const int C  = in_sizes[2] / D;       // 1000
    const int NT = (C + BN - 1) / BN;     // 8
    const int CP = NT * BN;               // 1024
    const int NB = Bt / BM;               // 256 rowblocks

    char* ws = (char*)d_ws;
    unsigned short* cbf = (unsigned short*)ws;          // CP*D bf16 = 1 MB
    size_t off = (size_t)CP * D * 2;
    off = (off + 255) & ~(size_t)255;
    float* pos = (float*)(ws + off);      off += (size_t)Bt * 4;       // 256 KB
    float* partial = (float*)(ws + off);  off += (size_t)NT * Bt * 4;  // 2 MB
    int* cnt = (int*)(ws + off);          off += (size_t)NB * 4;
    off = (off + 255) & ~(size_t)255;
    unsigned short* xbf = (unsigned short*)(ws + off);   // 64 MB

    const size_t nx = (size_t)Bt * D;
    const int CB = CP / 4;                                // center blocks
    const int XB = (int)((nx / 8 + 255) / 256);           // convert blocks
    prep<<<CB + XB, 256, 0, stream>>>(centers, cbf, C, D, CP, CB, x, xbf, nx,
                                      cnt, NB, out);

    gemm_fused<<<NB * NT, 512, 0, stream>>>(xbf, cbf, labels, pos, partial, cnt,
                                            Bt, C, D, NT, 1.0f, out);
}